// Round 15
// baseline (64.993 us; speedup 1.0000x reference)
//
#include <hip/hip_runtime.h>
#include <math.h>
#include <stdint.h>

// Router: scores = x @ emb^T [32768 x 64] fp32-accurate, top-2 + 2-way softmax.
//
// Error-free split-bf16 MFMA (rounds 9-14, passes): 3 bf16 limbs per fp32
// operand, 6 limb-product MFMA passes accumulated in fp32 (~3e-7 error).
// Round-14 null result: counted vmcnt on x-staging changed nothing -> the
// stall is the remaining RAW VMEM in the loop: B-frag loads from wsb, sunk by
// the compiler to their MFMA uses (~300cyc L2 exposure x 32 kk, unhidden at
// 4 waves/SIMD). This round the main loop has ZERO raw VMEM: B-frags are
// DMA-staged through LDS alongside x, from a chunk-contiguous prepack layout
// (stage addr = base + tid*16, the gload_lds requirement). Double-buffered,
// 2 barriers/chunk, counted vmcnt(4) over a now-CLEAN counter (4 stage
// loads/thread/chunk, nothing else increments vmcnt in-loop).
// Block = 512 thr = 8 waves = 2 token-halves (m) x 4 expert-tiles (t);
// per kk/wave: 2 swizzled ds_read_b128 + 1 split8 + 3 B ds_read + 6 MFMA.

typedef __attribute__((ext_vector_type(8))) short short8;
typedef __attribute__((ext_vector_type(4))) float f32x4;

constexpr int HDIM = 1024;
constexpr int NEXP = 64;
constexpr int TPB  = 32;            // tokens per block
constexpr int NTHREADS = 512;       // 8 waves
constexpr int NCHUNK = 16;          // 64-k chunks

__device__ __forceinline__ uint32_t cvtpk_bf16(float lo, float hi) {
    uint32_t r;
    asm("v_cvt_pk_bf16_f32 %0, %1, %2" : "=v"(r) : "v"(lo), "v"(hi));
    return r;
}

// RNE 3-limb bf16 split of 8 fp32 values; outputs packed frag words.
__device__ __forceinline__ void split8(const float4& A, const float4& B,
                                       uint32_t w0[4], uint32_t w1[4],
                                       uint32_t w2[4])
{
    const float p[8] = {A.x, A.y, A.z, A.w, B.x, B.y, B.z, B.w};
#pragma unroll
    for (int m = 0; m < 4; ++m) {
        const float lo = p[2 * m], hi = p[2 * m + 1];
        const uint32_t c0 = cvtpk_bf16(lo, hi);
        const float l0 = __uint_as_float(c0 << 16);
        const float h0 = __uint_as_float(c0 & 0xFFFF0000u);
        const float rl = lo - l0, rh = hi - h0;         // exact
        const uint32_t c1 = cvtpk_bf16(rl, rh);
        const float l1 = __uint_as_float(c1 << 16);
        const float h1 = __uint_as_float(c1 & 0xFFFF0000u);
        const uint32_t c2 = cvtpk_bf16(rl - l1, rh - h1);
        w0[m] = c0; w1[m] = c1; w2[m] = c2;
    }
}

__device__ __forceinline__ short8 frag_of(uint32_t a, uint32_t b,
                                          uint32_t c, uint32_t d) {
    union { uint4 u; short8 s; } cv;
    cv.u = make_uint4(a, b, c, d);
    return cv.s;
}
__device__ __forceinline__ short8 frag_of4(const uint4& v) {
    union { uint4 u; short8 s; } cv;
    cv.u = v;
    return cv.s;
}

// prepack, chunk-contiguous for linear staging:
// wsb[c*1536 + ((jkk*4 + t)*3 + limb)*64 + lane] =
//   limb of emb[t*16+(lane&15)][(c*2+jkk)*32 + (lane>>4)*8 .. +7] as bf16x8.
__global__ __launch_bounds__(256)
void prepack_kernel(const float* __restrict__ emb, uint4* __restrict__ wsb)
{
    const int f2   = blockIdx.x * 256 + threadIdx.x;   // 0..8191
    const int lane = f2 & 63;
    const int t    = (f2 >> 6) & 3;
    const int jkk  = (f2 >> 8) & 1;
    const int c    = f2 >> 9;
    const int e    = t * 16 + (lane & 15);
    const int k0   = (c * 2 + jkk) * 32 + (lane >> 4) * 8;
    const float4 A = *(const float4*)(emb + (size_t)e * HDIM + k0);
    const float4 B = *(const float4*)(emb + (size_t)e * HDIM + k0 + 4);
    uint32_t w0[4], w1[4], w2[4];
    split8(A, B, w0, w1, w2);
    const int ob = c * 1536 + ((jkk * 4 + t) * 3) * 64 + lane;
    wsb[ob]       = make_uint4(w0[0], w0[1], w0[2], w0[3]);
    wsb[ob + 64]  = make_uint4(w1[0], w1[1], w1[2], w1[3]);
    wsb[ob + 128] = make_uint4(w2[0], w2[1], w2[2], w2[3]);
}

__global__ __launch_bounds__(NTHREADS, 4)
void router_kernel(const float* __restrict__ x,
                   const uint4* __restrict__ wsb,
                   float* __restrict__ out)
{
    __shared__ float4 xs[2][TPB][16];   // 16 KiB, x[token][quad^(token&15)]
    __shared__ uint4  bs[2][1536];      // 48 KiB, staged B-frags (chunk image)
    __shared__ float4 cand[4][TPB];     // 2 KiB  (V1,E1,V2,E2) per tile/token
    __shared__ float4 cand2[TPB];       // 0.5 KiB (p1,p2,E1,E2) per token

    const int tid  = threadIdx.x;
    const int lane = tid & 63;
    const int W    = tid >> 6;          // wave 0..7
    const int m    = W >> 2;            // token half: rows 16m..16m+15
    const int t    = W & 3;             // expert tile: experts [16t, 16t+16)
    const int tok0 = blockIdx.x * TPB;
    const int col  = lane & 15;
    const int grp  = lane >> 4;

    // Stage chunk C into buffer P: x 8 KB (1 load/thread, XOR swizzle folded
    // into global source) + B 24 KB (3 loads/thread, chunk-contiguous wsb).
    // All dests are base + tid*16 (gload_lds linear requirement).
#define STAGE(P, C)                                                            \
    do {                                                                       \
        {                                                                      \
            const int r_ = tid >> 4, q_ = tid & 15;                            \
            const float* src = x + (size_t)(tok0 + r_) * HDIM + (C) * 64       \
                                 + ((q_ ^ (r_ & 15)) * 4);                     \
            __builtin_amdgcn_global_load_lds(                                  \
                (const __attribute__((address_space(1))) void*)src,            \
                (__attribute__((address_space(3))) void*)&xs[P][r_][q_],       \
                16, 0, 0);                                                     \
        }                                                                      \
        _Pragma("unroll")                                                      \
        for (int jj = 0; jj < 3; ++jj) {                                       \
            const int f_ = jj * NTHREADS + tid;                                \
            __builtin_amdgcn_global_load_lds(                                  \
                (const __attribute__((address_space(1))) void*)                \
                    (wsb + (C) * 1536 + f_),                                   \
                (__attribute__((address_space(3))) void*)&bs[P][f_],           \
                16, 0, 0);                                                     \
        }                                                                      \
    } while (0)

    f32x4 acc = {0, 0, 0, 0};           // 16 tokens (rows) x 16 experts (cols)

    STAGE(0, 0);
    STAGE(1, 1);

#pragma unroll 1
    for (int c = 0; c < NCHUNK; ++c) {
        // clean counted wait: 4 loads/stage/thread; outstanding = {c, c+1}.
        if (c < NCHUNK - 2) {
            asm volatile("s_waitcnt vmcnt(4)" ::: "memory");
        } else if (c == NCHUNK - 2) {
            asm volatile("s_waitcnt vmcnt(4)" ::: "memory");
        } else {
            asm volatile("s_waitcnt vmcnt(0)" ::: "memory");
        }
        __builtin_amdgcn_s_barrier();
        asm volatile("" ::: "memory");

        const int p = c & 1;
#pragma unroll
        for (int jkk = 0; jkk < 2; ++jkk) {
            const int q0 = jkk * 8 + grp * 2;
            const float4 a0 = xs[p][16 * m + col][(q0    ) ^ col];
            const float4 a1 = xs[p][16 * m + col][(q0 + 1) ^ col];

            uint32_t wa0[4], wa1[4], wa2[4];
            split8(a0, a1, wa0, wa1, wa2);
            const short8 fA0 = frag_of(wa0[0], wa0[1], wa0[2], wa0[3]);
            const short8 fA1 = frag_of(wa1[0], wa1[1], wa1[2], wa1[3]);
            const short8 fA2 = frag_of(wa2[0], wa2[1], wa2[2], wa2[3]);

            const int bf = ((jkk * 4 + t) * 3) * 64 + lane;
            const short8 fb0 = frag_of4(bs[p][bf]);
            const short8 fb1 = frag_of4(bs[p][bf + 64]);
            const short8 fb2 = frag_of4(bs[p][bf + 128]);

            acc = __builtin_amdgcn_mfma_f32_16x16x32_bf16(fA2, fb0, acc, 0,0,0);
            acc = __builtin_amdgcn_mfma_f32_16x16x32_bf16(fA0, fb2, acc, 0,0,0);
            acc = __builtin_amdgcn_mfma_f32_16x16x32_bf16(fA1, fb1, acc, 0,0,0);
            acc = __builtin_amdgcn_mfma_f32_16x16x32_bf16(fA1, fb0, acc, 0,0,0);
            acc = __builtin_amdgcn_mfma_f32_16x16x32_bf16(fA0, fb1, acc, 0,0,0);
            acc = __builtin_amdgcn_mfma_f32_16x16x32_bf16(fA0, fb0, acc, 0,0,0);
        }

        __builtin_amdgcn_s_barrier();   // all reads of buffer p complete
        asm volatile("" ::: "memory");
        if (c + 2 < NCHUNK) STAGE(p, c + 2);
    }
#undef STAGE

    // ---- top-2 epilogue. acc[i]: token 16m+grp*4+i, expert 16t+col.
    // Reduce over the 16-lane group (masks 1,2,4,8); lowest index wins ties.
#define INS(v, e)                                                              \
    do {                                                                       \
        const float _v = (v); const int _e = (e);                              \
        if (_v > V1 || (_v == V1 && _e < E1)) {                                \
            V2 = V1; E2 = E1; V1 = _v; E1 = _e;                                \
        } else if (_v > V2 || (_v == V2 && _e < E2)) {                         \
            V2 = _v; E2 = _e;                                                  \
        }                                                                      \
    } while (0)

#pragma unroll
    for (int i = 0; i < 4; ++i) {
        float V1 = acc[i]; int E1 = 16 * t + col;
        float V2 = -INFINITY; int E2 = NEXP;
#pragma unroll
        for (int mk = 1; mk <= 8; mk <<= 1) {
            const float pv1 = __shfl_xor(V1, mk, 64);
            const int   pe1 = __shfl_xor(E1, mk, 64);
            const float pv2 = __shfl_xor(V2, mk, 64);
            const int   pe2 = __shfl_xor(E2, mk, 64);
            INS(pv1, pe1);
            INS(pv2, pe2);
        }
        if (col == 0) {
            float4 cd;
            cd.x = V1; cd.y = __int_as_float(E1);
            cd.z = V2; cd.w = __int_as_float(E2);
            cand[t][16 * m + grp * 4 + i] = cd;
        }
    }
    __syncthreads();

    // ---- merge 4 expert tiles per token (ascending tile => lowest-idx ties)
    if (tid < TPB) {
        float V1 = -INFINITY, V2 = -INFINITY; int E1 = 0, E2 = 0;
#pragma unroll
        for (int tt = 0; tt < 4; ++tt) {
            const float4 q = cand[tt][tid];
            const float a = q.x; const int ea = __float_as_int(q.y);
            const float b = q.z; const int eb = __float_as_int(q.w);
            if (a > V1)      { V2 = V1; E2 = E1; V1 = a; E1 = ea; }
            else if (a > V2) { V2 = a; E2 = ea; }
            if (b > V1)      { V2 = V1; E2 = E1; V1 = b; E1 = eb; }
            else if (b > V2) { V2 = b; E2 = eb; }
        }
        const float et = expf(V2 - V1);
        float4 c2;
        c2.x = 1.f / (1.f + et);
        c2.y = et / (1.f + et);
        c2.z = __int_as_float(E1);
        c2.w = __int_as_float(E2);
        cand2[tid] = c2;
    }
#undef INS
    __syncthreads();

    // ---- coalesced output: 32 tokens x 16 quads = 512 float4 (1/thread) ----
    {
        const int tt = tid >> 4, q = tid & 15;
        const float4 c = cand2[tt];
        const int E1 = __float_as_int(c.z), E2 = __float_as_int(c.w);
        float4 o;
        float* of = (float*)&o;
#pragma unroll
        for (int ii = 0; ii < 4; ++ii) {
            const int e = 4 * q + ii;
            of[ii] = (e == E1) ? c.x : (e == E2) ? c.y : 0.f;
        }
        *(float4*)(out + (size_t)(tok0 + tt) * NEXP + q * 4) = o;
    }
}

extern "C" void kernel_launch(void* const* d_in, const int* in_sizes, int n_in,
                              void* d_out, int out_size, void* d_ws, size_t ws_size,
                              hipStream_t stream)
{
    const float* x   = (const float*)d_in[0];
    const float* emb = (const float*)d_in[1];
    float* out = (float*)d_out;
    uint4* wsb = (uint4*)d_ws;                   // 384 KiB chunk-contiguous frags

    prepack_kernel<<<32, 256, 0, stream>>>(emb, wsb);

    const int n_tokens = in_sizes[0] / HDIM;     // 32768
    const int nblocks  = n_tokens / TPB;         // 1024

    router_kernel<<<nblocks, NTHREADS, 0, stream>>>(x, wsb, out);
}

// Round 16
// 59.244 us; speedup vs baseline: 1.0970x; 1.0970x over previous
//
#include <hip/hip_runtime.h>
#include <math.h>
#include <stdint.h>

// Router: scores = x @ emb^T [32768 x 64] fp32-accurate, top-2 + 2-way softmax.
//
// Error-free split-bf16 MFMA (rounds 9-15, passes): 3 bf16 limbs per fp32
// operand, 6 limb-product MFMA passes accumulated in fp32 (~3e-7 error).
// Rounds 13-15 plateaued at 61-65us with every pipe <45% busy: the dominant
// term is the B-frag CACHE STREAM -- 1024 blocks x 384 KB = 393 MB through
// L2/L3 -- plus x 134 MB. This round halves it: TPB=64 (512 blocks x 384 KB
// = 196 MB) at UNCHANGED occupancy. 512 thr = 8 waves = 2 token-halves x 4
// expert tiles; wave = 32 tokens x 16 experts (2 f32x4 acc). LDS = exactly
// 80 KB (x dbuf 32K + B dbuf 48K) = 2 blocks/CU = 4 waves/SIMD; epilogue
// candidate buffers ALIAS into xs (no extra LDS). Clean counted vmcnt(5)
// (5 stage loads/thread/chunk, zero other VMEM in loop).

typedef __attribute__((ext_vector_type(8))) short short8;
typedef __attribute__((ext_vector_type(4))) float f32x4;

constexpr int HDIM = 1024;
constexpr int NEXP = 64;
constexpr int TPB  = 64;            // tokens per block
constexpr int NTHREADS = 512;       // 8 waves
constexpr int NCHUNK = 16;          // 64-k chunks

__device__ __forceinline__ uint32_t cvtpk_bf16(float lo, float hi) {
    uint32_t r;
    asm("v_cvt_pk_bf16_f32 %0, %1, %2" : "=v"(r) : "v"(lo), "v"(hi));
    return r;
}

// RNE 3-limb bf16 split of 8 fp32 values; outputs packed frag words.
__device__ __forceinline__ void split8(const float4& A, const float4& B,
                                       uint32_t w0[4], uint32_t w1[4],
                                       uint32_t w2[4])
{
    const float p[8] = {A.x, A.y, A.z, A.w, B.x, B.y, B.z, B.w};
#pragma unroll
    for (int m = 0; m < 4; ++m) {
        const float lo = p[2 * m], hi = p[2 * m + 1];
        const uint32_t c0 = cvtpk_bf16(lo, hi);
        const float l0 = __uint_as_float(c0 << 16);
        const float h0 = __uint_as_float(c0 & 0xFFFF0000u);
        const float rl = lo - l0, rh = hi - h0;         // exact
        const uint32_t c1 = cvtpk_bf16(rl, rh);
        const float l1 = __uint_as_float(c1 << 16);
        const float h1 = __uint_as_float(c1 & 0xFFFF0000u);
        const uint32_t c2 = cvtpk_bf16(rl - l1, rh - h1);
        w0[m] = c0; w1[m] = c1; w2[m] = c2;
    }
}

__device__ __forceinline__ short8 frag_of(uint32_t a, uint32_t b,
                                          uint32_t c, uint32_t d) {
    union { uint4 u; short8 s; } cv;
    cv.u = make_uint4(a, b, c, d);
    return cv.s;
}
__device__ __forceinline__ short8 frag_of4(const uint4& v) {
    union { uint4 u; short8 s; } cv;
    cv.u = v;
    return cv.s;
}

// prepack, chunk-contiguous for linear staging (same layout as round 15):
// wsb[c*1536 + ((jkk*4 + t)*3 + limb)*64 + lane] =
//   limb of emb[t*16+(lane&15)][(c*2+jkk)*32 + (lane>>4)*8 .. +7] as bf16x8.
__global__ __launch_bounds__(256)
void prepack_kernel(const float* __restrict__ emb, uint4* __restrict__ wsb)
{
    const int f2   = blockIdx.x * 256 + threadIdx.x;   // 0..8191
    const int lane = f2 & 63;
    const int t    = (f2 >> 6) & 3;
    const int jkk  = (f2 >> 8) & 1;
    const int c    = f2 >> 9;
    const int e    = t * 16 + (lane & 15);
    const int k0   = (c * 2 + jkk) * 32 + (lane >> 4) * 8;
    const float4 A = *(const float4*)(emb + (size_t)e * HDIM + k0);
    const float4 B = *(const float4*)(emb + (size_t)e * HDIM + k0 + 4);
    uint32_t w0[4], w1[4], w2[4];
    split8(A, B, w0, w1, w2);
    const int ob = c * 1536 + ((jkk * 4 + t) * 3) * 64 + lane;
    wsb[ob]       = make_uint4(w0[0], w0[1], w0[2], w0[3]);
    wsb[ob + 64]  = make_uint4(w1[0], w1[1], w1[2], w1[3]);
    wsb[ob + 128] = make_uint4(w2[0], w2[1], w2[2], w2[3]);
}

__global__ __launch_bounds__(NTHREADS, 4)
void router_kernel(const float* __restrict__ x,
                   const uint4* __restrict__ wsb,
                   float* __restrict__ out)
{
    // Exactly 80 KB: 2 blocks/CU fill the 160 KiB LDS with zero slack.
    __shared__ float4 xs[2][TPB][16];   // 32 KiB, x[token][quad^(token&15)]
    __shared__ uint4  bs[2][1536];      // 48 KiB, staged B-frags (chunk image)

    const int tid  = threadIdx.x;
    const int lane = tid & 63;
    const int W    = tid >> 6;          // wave 0..7
    const int m    = W >> 2;            // token half: rows 32m..32m+31
    const int t    = W & 3;             // expert tile: experts [16t, 16t+16)
    const int tok0 = blockIdx.x * TPB;
    const int col  = lane & 15;
    const int grp  = lane >> 4;

    // Stage chunk C into buffer P: x 16 KB (2 loads/thread, XOR swizzle folded
    // into global source) + B 24 KB (3 loads/thread). All dests linear in tid.
#define STAGE(P, C)                                                            \
    do {                                                                       \
        _Pragma("unroll")                                                      \
        for (int jj = 0; jj < 2; ++jj) {                                       \
            const int g_ = jj * NTHREADS + tid;                                \
            const int r_ = g_ >> 4, q_ = g_ & 15;                              \
            const float* src = x + (size_t)(tok0 + r_) * HDIM + (C) * 64       \
                                 + ((q_ ^ (r_ & 15)) * 4);                     \
            __builtin_amdgcn_global_load_lds(                                  \
                (const __attribute__((address_space(1))) void*)src,            \
                (__attribute__((address_space(3))) void*)&xs[P][r_][q_],       \
                16, 0, 0);                                                     \
        }                                                                      \
        _Pragma("unroll")                                                      \
        for (int jj = 0; jj < 3; ++jj) {                                       \
            const int f_ = jj * NTHREADS + tid;                                \
            __builtin_amdgcn_global_load_lds(                                  \
                (const __attribute__((address_space(1))) void*)                \
                    (wsb + (C) * 1536 + f_),                                   \
                (__attribute__((address_space(3))) void*)&bs[P][f_],           \
                16, 0, 0);                                                     \
        }                                                                      \
    } while (0)

    f32x4 accA = {0, 0, 0, 0};          // tokens 32m+0..15  x experts 16t..+15
    f32x4 accB = {0, 0, 0, 0};          // tokens 32m+16..31 x experts 16t..+15

    STAGE(0, 0);
    STAGE(1, 1);

#pragma unroll 1
    for (int c = 0; c < NCHUNK; ++c) {
        // clean counted wait: 5 loads/stage/thread; outstanding = {c, c+1}.
        if (c < NCHUNK - 1) {
            asm volatile("s_waitcnt vmcnt(5)" ::: "memory");
        } else {
            asm volatile("s_waitcnt vmcnt(0)" ::: "memory");
        }
        __builtin_amdgcn_s_barrier();
        asm volatile("" ::: "memory");

        const int p = c & 1;
#pragma unroll
        for (int jkk = 0; jkk < 2; ++jkk) {
            const int q0 = jkk * 8 + grp * 2;
            const int rA = 32 * m + col, rB = 32 * m + 16 + col;
            const float4 a0 = xs[p][rA][(q0    ) ^ col];
            const float4 a1 = xs[p][rA][(q0 + 1) ^ col];
            const float4 b0 = xs[p][rB][(q0    ) ^ col];
            const float4 b1 = xs[p][rB][(q0 + 1) ^ col];

            uint32_t wa0[4], wa1[4], wa2[4], wb0[4], wb1[4], wb2[4];
            split8(a0, a1, wa0, wa1, wa2);
            split8(b0, b1, wb0, wb1, wb2);
            const short8 fA0 = frag_of(wa0[0], wa0[1], wa0[2], wa0[3]);
            const short8 fA1 = frag_of(wa1[0], wa1[1], wa1[2], wa1[3]);
            const short8 fA2 = frag_of(wa2[0], wa2[1], wa2[2], wa2[3]);
            const short8 fB0 = frag_of(wb0[0], wb0[1], wb0[2], wb0[3]);
            const short8 fB1 = frag_of(wb1[0], wb1[1], wb1[2], wb1[3]);
            const short8 fB2 = frag_of(wb2[0], wb2[1], wb2[2], wb2[3]);

            const int bf = ((jkk * 4 + t) * 3) * 64 + lane;
            const short8 fb0 = frag_of4(bs[p][bf]);
            const short8 fb1 = frag_of4(bs[p][bf + 64]);
            const short8 fb2 = frag_of4(bs[p][bf + 128]);

            accA = __builtin_amdgcn_mfma_f32_16x16x32_bf16(fA2, fb0, accA, 0,0,0);
            accA = __builtin_amdgcn_mfma_f32_16x16x32_bf16(fA0, fb2, accA, 0,0,0);
            accA = __builtin_amdgcn_mfma_f32_16x16x32_bf16(fA1, fb1, accA, 0,0,0);
            accA = __builtin_amdgcn_mfma_f32_16x16x32_bf16(fA1, fb0, accA, 0,0,0);
            accA = __builtin_amdgcn_mfma_f32_16x16x32_bf16(fA0, fb1, accA, 0,0,0);
            accA = __builtin_amdgcn_mfma_f32_16x16x32_bf16(fA0, fb0, accA, 0,0,0);

            accB = __builtin_amdgcn_mfma_f32_16x16x32_bf16(fB2, fb0, accB, 0,0,0);
            accB = __builtin_amdgcn_mfma_f32_16x16x32_bf16(fB0, fb2, accB, 0,0,0);
            accB = __builtin_amdgcn_mfma_f32_16x16x32_bf16(fB1, fb1, accB, 0,0,0);
            accB = __builtin_amdgcn_mfma_f32_16x16x32_bf16(fB1, fb0, accB, 0,0,0);
            accB = __builtin_amdgcn_mfma_f32_16x16x32_bf16(fB0, fb1, accB, 0,0,0);
            accB = __builtin_amdgcn_mfma_f32_16x16x32_bf16(fB0, fb0, accB, 0,0,0);
        }

        __builtin_amdgcn_s_barrier();   // all reads of buffer p complete
        asm volatile("" ::: "memory");
        if (c + 2 < NCHUNK) STAGE(p, c + 2);
    }
#undef STAGE

    // ---- epilogue: alias candidate buffers into xs (loop is done) ----
    __syncthreads();
    float4* cand  = &xs[0][0][0];       // [4 tiles][64 tokens]
    float4* cand2 = &xs[1][0][0];       // [64 tokens] (p1,p2,E1,E2)

#define INS(v, e)                                                              \
    do {                                                                       \
        const float _v = (v); const int _e = (e);                              \
        if (_v > V1 || (_v == V1 && _e < E1)) {                                \
            V2 = V1; E2 = E1; V1 = _v; E1 = _e;                                \
        } else if (_v > V2 || (_v == V2 && _e < E2)) {                         \
            V2 = _v; E2 = _e;                                                  \
        }                                                                      \
    } while (0)

#pragma unroll
    for (int i = 0; i < 4; ++i) {
        {   // accA: token 32m + grp*4 + i, expert 16t+col
            float V1 = accA[i]; int E1 = 16 * t + col;
            float V2 = -INFINITY; int E2 = NEXP;
#pragma unroll
            for (int mk = 1; mk <= 8; mk <<= 1) {
                const float pv1 = __shfl_xor(V1, mk, 64);
                const int   pe1 = __shfl_xor(E1, mk, 64);
                const float pv2 = __shfl_xor(V2, mk, 64);
                const int   pe2 = __shfl_xor(E2, mk, 64);
                INS(pv1, pe1);
                INS(pv2, pe2);
            }
            if (col == 0) {
                float4 cd;
                cd.x = V1; cd.y = __int_as_float(E1);
                cd.z = V2; cd.w = __int_as_float(E2);
                cand[t * 64 + 32 * m + grp * 4 + i] = cd;
            }
        }
        {   // accB: token 32m + 16 + grp*4 + i
            float V1 = accB[i]; int E1 = 16 * t + col;
            float V2 = -INFINITY; int E2 = NEXP;
#pragma unroll
            for (int mk = 1; mk <= 8; mk <<= 1) {
                const float pv1 = __shfl_xor(V1, mk, 64);
                const int   pe1 = __shfl_xor(E1, mk, 64);
                const float pv2 = __shfl_xor(V2, mk, 64);
                const int   pe2 = __shfl_xor(E2, mk, 64);
                INS(pv1, pe1);
                INS(pv2, pe2);
            }
            if (col == 0) {
                float4 cd;
                cd.x = V1; cd.y = __int_as_float(E1);
                cd.z = V2; cd.w = __int_as_float(E2);
                cand[t * 64 + 32 * m + 16 + grp * 4 + i] = cd;
            }
        }
    }
    __syncthreads();

    // ---- merge 4 expert tiles per token (ascending tile => lowest-idx ties)
    if (tid < TPB) {
        float V1 = -INFINITY, V2 = -INFINITY; int E1 = 0, E2 = 0;
#pragma unroll
        for (int tt = 0; tt < 4; ++tt) {
            const float4 q = cand[tt * 64 + tid];
            const float a = q.x; const int ea = __float_as_int(q.y);
            const float b = q.z; const int eb = __float_as_int(q.w);
            if (a > V1)      { V2 = V1; E2 = E1; V1 = a; E1 = ea; }
            else if (a > V2) { V2 = a; E2 = ea; }
            if (b > V1)      { V2 = V1; E2 = E1; V1 = b; E1 = eb; }
            else if (b > V2) { V2 = b; E2 = eb; }
        }
        const float et = expf(V2 - V1);
        float4 c2;
        c2.x = 1.f / (1.f + et);
        c2.y = et / (1.f + et);
        c2.z = __int_as_float(E1);
        c2.w = __int_as_float(E2);
        cand2[tid] = c2;
    }
#undef INS
    __syncthreads();

    // ---- coalesced output: 64 tokens x 16 quads = 1024 float4 (2/thread) ----
#pragma unroll
    for (int jj = 0; jj < 2; ++jj) {
        const int G = jj * NTHREADS + tid;     // 0..1023
        const int tt = G >> 4, q = G & 15;
        const float4 c = cand2[tt];
        const int E1 = __float_as_int(c.z), E2 = __float_as_int(c.w);
        float4 o;
        float* of = (float*)&o;
#pragma unroll
        for (int ii = 0; ii < 4; ++ii) {
            const int e = 4 * q + ii;
            of[ii] = (e == E1) ? c.x : (e == E2) ? c.y : 0.f;
        }
        *(float4*)(out + (size_t)(tok0 + tt) * NEXP + q * 4) = o;
    }
}

extern "C" void kernel_launch(void* const* d_in, const int* in_sizes, int n_in,
                              void* d_out, int out_size, void* d_ws, size_t ws_size,
                              hipStream_t stream)
{
    const float* x   = (const float*)d_in[0];
    const float* emb = (const float*)d_in[1];
    float* out = (float*)d_out;
    uint4* wsb = (uint4*)d_ws;                   // 384 KiB chunk-contiguous frags

    prepack_kernel<<<32, 256, 0, stream>>>(emb, wsb);

    const int n_tokens = in_sizes[0] / HDIM;     // 32768
    const int nblocks  = n_tokens / TPB;         // 512

    router_kernel<<<nblocks, NTHREADS, 0, stream>>>(x, wsb, out);
}